// Round 11
// baseline (246.357 us; speedup 1.0000x reference)
//
#include <hip/hip_runtime.h>
#include <hip/hip_bf16.h>

#define N_NODES 50000
#define N_EDGES 800000
#define F_IN 128
#define HH 128                   // HEADS*HID
#define HEADS 4
#define HID 32
#define NCLS 16
#define NEG 0.2f
#define CAP 96                   // bucket capacity; in-deg ~ Pois(16), max << 96
#define MAXD 64                  // LDS-cached edges per node (global fallback beyond)
#define FILL_BLOCKS ((N_EDGES + 255) / 256)      // 3125
#define GEMM_BLOCKS ((N_NODES + 63) / 64)        // 782

typedef unsigned short u16;
typedef short bf16x8 __attribute__((ext_vector_type(8)));
typedef float f32x4 __attribute__((ext_vector_type(4)));
typedef u16 u16x8 __attribute__((ext_vector_type(8)));

__device__ __forceinline__ float lrelu(float x) { return x > 0.f ? x : NEG * x; }
__device__ __forceinline__ float bu2f(u16 u) { return __uint_as_float(((unsigned)u) << 16); }
__device__ __forceinline__ u16 f2bu(float f) {
    __hip_bfloat16 h = __float2bfloat16(f);
    return *reinterpret_cast<u16*>(&h);
}

// ------- fused prologue: blocks [0,FILL) bucket-fill; blocks [FILL,..) MFMA gemm1 -------
__global__ void __launch_bounds__(256) k_pre(
        const int* __restrict__ ei, int* __restrict__ cnt, int* __restrict__ esrc,
        const float* __restrict__ x, const float* __restrict__ W1,
        const float* __restrict__ a_s, const float* __restrict__ a_d,
        u16* __restrict__ h1b, float* __restrict__ al_s, float* __restrict__ al_d) {
    __shared__ u16 w1t[128 * 136];   // gemm path only; stride 136 (16B-aligned rows)
    int t = threadIdx.x;
    if ((int)blockIdx.x < FILL_BLOCKS) {
        // ---- bucket fill (real edges only; self-loops analytic in agg) ----
        int i = blockIdx.x * 256 + t;
        if (i < N_EDGES) {
            int s = ei[i], d = ei[N_EDGES + i];
            int pos = atomicAdd(&cnt[d], 1);
            if (pos < CAP) __builtin_nontemporal_store(s, &esrc[d * CAP + pos]);
        }
        return;
    }
    // ---- gemm1: h1b (bf16) = x @ W1, + attention logits ----
    int bb = blockIdx.x - FILL_BLOCKS;
    for (int it = 0; it < 64; ++it) {
        int idx = it * 256 + t;              // idx = k*128 + n
        int k = idx >> 7, n = idx & 127;
        w1t[n * 136 + k] = f2bu(W1[idx]);
    }
    __syncthreads();
    int wave = t >> 6, lane = t & 63;
    int col = lane & 15, quad = lane >> 4;
    int tb = bb * 64 + wave * 16;
    union { bf16x8 v; u16 u[8]; } af[4];
    int anode = tb + col;
    bool aval = anode < N_NODES;
    const float* xr = x + (size_t)anode * F_IN + quad * 8;
#pragma unroll
    for (int kb = 0; kb < 4; ++kb) {
        float4 lo = aval ? ((const float4*)(xr + kb * 32))[0] : make_float4(0.f, 0.f, 0.f, 0.f);
        float4 hi = aval ? ((const float4*)(xr + kb * 32))[1] : make_float4(0.f, 0.f, 0.f, 0.f);
        af[kb].u[0] = f2bu(lo.x); af[kb].u[1] = f2bu(lo.y);
        af[kb].u[2] = f2bu(lo.z); af[kb].u[3] = f2bu(lo.w);
        af[kb].u[4] = f2bu(hi.x); af[kb].u[5] = f2bu(hi.y);
        af[kb].u[6] = f2bu(hi.z); af[kb].u[7] = f2bu(hi.w);
    }
    float ps[4][4] = {}, pd[4][4] = {};
#pragma unroll
    for (int nt = 0; nt < 8; ++nt) {
        f32x4 acc = {0.f, 0.f, 0.f, 0.f};
#pragma unroll
        for (int kb = 0; kb < 4; ++kb) {
            bf16x8 bf = *(const bf16x8*)&w1t[(nt * 16 + col) * 136 + kb * 32 + quad * 8];
            acc = __builtin_amdgcn_mfma_f32_16x16x32_bf16(af[kb].v, bf, acc, 0, 0, 0);
        }
        int feat = nt * 16 + col;
        float asv = a_s[feat], adv = a_d[feat];
        const int head = nt >> 1;
#pragma unroll
        for (int r = 0; r < 4; ++r) {
            int node = tb + quad * 4 + r;
            float v = acc[r];
            if (node < N_NODES) h1b[(size_t)node * HH + feat] = f2bu(v);
            ps[r][head] = fmaf(v, asv, ps[r][head]);
            pd[r][head] = fmaf(v, adv, pd[r][head]);
        }
    }
#pragma unroll
    for (int r = 0; r < 4; ++r)
#pragma unroll
        for (int h = 0; h < 4; ++h)
#pragma unroll
            for (int w = 1; w < 16; w <<= 1) {
                ps[r][h] += __shfl_xor(ps[r][h], w);
                pd[r][h] += __shfl_xor(pd[r][h], w);
            }
    if (col == 0) {
#pragma unroll
        for (int r = 0; r < 4; ++r) {
            int node = tb + quad * 4 + r;
            if (node < N_NODES) {
#pragma unroll
                for (int h = 0; h < 4; ++h) {
                    al_s[node * 4 + h] = ps[r][h];
                    al_d[node * 4 + h] = pd[r][h];
                }
            }
        }
    }
}

// ---------------- layer 1 aggregate + fused layer-2 GEMM + layer-2 logits ----------------
__global__ void __launch_bounds__(256) k_agg1(
        const int* __restrict__ esrc, const int* __restrict__ cnt,
        const float* __restrict__ alS, const float* __restrict__ alD,
        const u16* __restrict__ h1b, const float* __restrict__ b1,
        const float* __restrict__ W2, const float* __restrict__ a_s2,
        const float* __restrict__ a_d2,
        u16* __restrict__ h2b, float* __restrict__ alS2, float* __restrict__ alD2) {
    __shared__ float wls[4][MAXD * HEADS];       // 4 KB
    __shared__ int   sls[4][MAXD];               // 1 KB
    __shared__ __align__(16) float rowf[4][HH];  // 2 KB
    __shared__ float w2t[NCLS * 132];            // 8.25 KB
    __shared__ float as2s[NCLS], ad2s[NCLS];
    int t = threadIdx.x;
    for (int idx = t; idx < F_IN * NCLS; idx += 256) {
        int f = idx >> 4, c = idx & 15;
        w2t[c * 132 + f] = W2[idx];
    }
    if (t < NCLS) { as2s[t] = a_s2[t]; ad2s[t] = a_d2[t]; }
    __syncthreads();
    int wave = t >> 6, lane = t & 63;
    int n = blockIdx.x * 4 + wave;               // grid = N/4 exactly
    int off = n * CAP;
    int deg = min(cnt[n], CAP);                  // real edges; e==deg is the self-loop
    // phase A: softmax weights + source cache; slot=lane&15, head=lane>>4
    int slot = lane & 15, h = lane >> 4;
    float ad = alD[n * 4 + h];
    float den = 0.f;
    for (int e = slot; e <= deg; e += 16) {
        int s = (e < deg) ? esrc[off + e] : n;
        float wv = __expf(lrelu(alS[s * 4 + h] + ad));
        if (e < MAXD) {
            wls[wave][e * 4 + h] = wv;
            if (h == 0) sls[wave][e] = s;
        }
        den += wv;
    }
#pragma unroll
    for (int w = 1; w < 16; w <<= 1) den += __shfl_xor(den, w);
    float inv = 1.f / den;
    // phase B: quarter-wave per edge (4 in flight) + 2-deep prefetch pipeline
    int quarter = lane >> 4, fl = lane & 15;
    int hb = fl >> 2;
    float invh = __shfl(inv, hb << 4);
    float adh = alD[n * 4 + hb];
    float acc[8] = {};
    int e = quarter;
    u16x8 qP; float wP = 0.f;
    if (e <= deg) {
        int s;
        if (e < MAXD) { s = sls[wave][e]; wP = wls[wave][e * 4 + hb]; }
        else { s = (e < deg) ? esrc[off + e] : n; wP = __expf(lrelu(alS[s * 4 + hb] + adh)); }
        qP = ((const u16x8*)(h1b + (size_t)s * HH))[fl];
    }
    while (e <= deg) {
        int e2 = e + 4;
        u16x8 qN; float wN = 0.f;
        if (e2 <= deg) {
            int s2;
            if (e2 < MAXD) { s2 = sls[wave][e2]; wN = wls[wave][e2 * 4 + hb]; }
            else { s2 = (e2 < deg) ? esrc[off + e2] : n; wN = __expf(lrelu(alS[s2 * 4 + hb] + adh)); }
            qN = ((const u16x8*)(h1b + (size_t)s2 * HH))[fl];
        }
        float a = wP * invh;
#pragma unroll
        for (int j = 0; j < 8; ++j)
            acc[j] = fmaf(bu2f(qP[j]), a, acc[j]);
        e = e2; qP = qN; wP = wN;
    }
#pragma unroll
    for (int j = 0; j < 8; ++j) {
        acc[j] += __shfl_xor(acc[j], 16);
        acc[j] += __shfl_xor(acc[j], 32);
    }
    if (quarter == 0) {
        const float4* b4 = (const float4*)b1;
        float4 blo = b4[fl * 2], bhi = b4[fl * 2 + 1];
        float v[8];
        v[0] = acc[0] + blo.x; v[1] = acc[1] + blo.y;
        v[2] = acc[2] + blo.z; v[3] = acc[3] + blo.w;
        v[4] = acc[4] + bhi.x; v[5] = acc[5] + bhi.y;
        v[6] = acc[6] + bhi.z; v[7] = acc[7] + bhi.w;
#pragma unroll
        for (int j = 0; j < 8; ++j) v[j] = v[j] > 0.f ? v[j] : __expf(v[j]) - 1.f;
        ((float4*)&rowf[wave][0])[fl * 2]     = make_float4(v[0], v[1], v[2], v[3]);
        ((float4*)&rowf[wave][0])[fl * 2 + 1] = make_float4(v[4], v[5], v[6], v[7]);
    }
    // fused gemm2 (same wave -> LDS RAW ordered): f = 4i+q conflict-free
    int c = lane & 15, q = lane >> 4;
    float h2acc = 0.f;
#pragma unroll
    for (int i = 0; i < 32; ++i) {
        int f = i * 4 + q;
        h2acc = fmaf(rowf[wave][f], w2t[c * 132 + f], h2acc);
    }
    h2acc += __shfl_xor(h2acc, 16);
    h2acc += __shfl_xor(h2acc, 32);
    if (lane < 16) h2b[(size_t)n * NCLS + lane] = f2bu(h2acc);
    float rs = h2acc * as2s[c], rd = h2acc * ad2s[c];
#pragma unroll
    for (int w = 1; w < 16; w <<= 1) { rs += __shfl_xor(rs, w); rd += __shfl_xor(rd, w); }
    if (lane == 0) { alS2[n] = rs; alD2[n] = rd; }
}

// ---------------- layer 2 aggregate + bias + log_softmax -> out ----------------
__global__ void __launch_bounds__(256) k_agg2(
        const int* __restrict__ esrc, const int* __restrict__ cnt,
        const float* __restrict__ alS2, const float* __restrict__ alD2,
        const u16* __restrict__ h2b, const float* __restrict__ b2,
        float* __restrict__ out) {
    __shared__ float wls[4][MAXD];   // 1 KB
    __shared__ int   sls[4][MAXD];   // 1 KB
    int wave = threadIdx.x >> 6, lane = threadIdx.x & 63;
    int n = blockIdx.x * 4 + wave;
    int off = n * CAP;
    int deg = min(cnt[n], CAP);
    float ad = alD2[n];
    float den = 0.f;
    for (int e = lane; e <= deg; e += 64) {
        int s = (e < deg) ? esrc[off + e] : n;
        float wv = __expf(lrelu(alS2[s] + ad));
        if (e < MAXD) { wls[wave][e] = wv; sls[wave][e] = s; }
        den += wv;
    }
#pragma unroll
    for (int w = 1; w < 64; w <<= 1) den += __shfl_xor(den, w);
    float inv = 1.f / den;
    // phase B: 8 edges in flight + 2-deep prefetch; lane handles classes 2cp, 2cp+1
    int sub = lane >> 3, cp = lane & 7;
    float a0 = 0.f, a1 = 0.f;
    int e = sub;
    unsigned qP = 0; float wP = 0.f;
    if (e <= deg) {
        int s;
        if (e < MAXD) { s = sls[wave][e]; wP = wls[wave][e]; }
        else { s = (e < deg) ? esrc[off + e] : n; wP = __expf(lrelu(alS2[s] + ad)); }
        qP = ((const unsigned*)(h2b + (size_t)s * NCLS))[cp];
    }
    while (e <= deg) {
        int e2 = e + 8;
        unsigned qN = 0; float wN = 0.f;
        if (e2 <= deg) {
            int s2;
            if (e2 < MAXD) { s2 = sls[wave][e2]; wN = wls[wave][e2]; }
            else { s2 = (e2 < deg) ? esrc[off + e2] : n; wN = __expf(lrelu(alS2[s2] + ad)); }
            qN = ((const unsigned*)(h2b + (size_t)s2 * NCLS))[cp];
        }
        float al = wP * inv;
        a0 = fmaf(bu2f((u16)(qP & 0xffffu)), al, a0);
        a1 = fmaf(bu2f((u16)(qP >> 16)), al, a1);
        e = e2; qP = qN; wP = wN;
    }
    a0 += __shfl_xor(a0, 8);  a1 += __shfl_xor(a1, 8);
    a0 += __shfl_xor(a0, 16); a1 += __shfl_xor(a1, 16);
    a0 += __shfl_xor(a0, 32); a1 += __shfl_xor(a1, 32);
    float v0 = a0 + b2[2 * cp], v1 = a1 + b2[2 * cp + 1];
    float mx = fmaxf(v0, v1);
#pragma unroll
    for (int w = 1; w < 8; w <<= 1) mx = fmaxf(mx, __shfl_xor(mx, w));
    float ex = __expf(v0 - mx) + __expf(v1 - mx);
#pragma unroll
    for (int w = 1; w < 8; w <<= 1) ex += __shfl_xor(ex, w);
    float lse = mx + __logf(ex);
    if (lane < 8) ((float2*)(out + (size_t)n * NCLS))[cp] = make_float2(v0 - lse, v1 - lse);
}

extern "C" void kernel_launch(void* const* d_in, const int* in_sizes, int n_in,
                              void* d_out, int out_size, void* d_ws, size_t ws_size,
                              hipStream_t stream) {
    const float* x   = (const float*)d_in[0];
    const int*   ei  = (const int*)d_in[1];
    const float* W1  = (const float*)d_in[2];
    const float* as1 = (const float*)d_in[3];
    const float* ad1 = (const float*)d_in[4];
    const float* b1  = (const float*)d_in[5];
    const float* W2  = (const float*)d_in[6];
    const float* as2 = (const float*)d_in[7];
    const float* ad2 = (const float*)d_in[8];
    const float* b2  = (const float*)d_in[9];
    float* out = (float*)d_out;
    char* ws = (char*)d_ws;

    u16*   h1b  = (u16*)  (ws);                 // N*128 bf16 = 12.8 MB
    float* alS1 = (float*)(ws + 12800000);      // N*4
    float* alD1 = (float*)(ws + 13600000);      // N*4
    u16*   h2b  = (u16*)  (ws + 14400000);      // N*16 bf16 = 1.6 MB
    float* alS2 = (float*)(ws + 16000000);      // N
    float* alD2 = (float*)(ws + 16200000);      // N
    int*   cnt  = (int*)  (ws + 16400000);      // N = 200 KB
    int*   esrc = (int*)  (ws + 16600000);      // N*CAP = 19.2 MB  (total ~35.8 MB)

    hipMemsetAsync(cnt, 0, (size_t)N_NODES * 4, stream);
    k_pre<<<FILL_BLOCKS + GEMM_BLOCKS, 256, 0, stream>>>(
        ei, cnt, esrc, x, W1, as1, ad1, h1b, alS1, alD1);
    k_agg1<<<N_NODES / 4, 256, 0, stream>>>(esrc, cnt, alS1, alD1, h1b, b1,
                                            W2, as2, ad2, h2b, alS2, alD2);
    k_agg2<<<N_NODES / 4, 256, 0, stream>>>(esrc, cnt, alS2, alD2, h2b, b2, out);
}